// Round 4
// baseline (798.204 us; speedup 1.0000x reference)
//
#include <hip/hip_runtime.h>
#include <cmath>

#define NTOK 1024
#define HD   768
#define FF   3072
#define NE   8
#define NSLOT (NTOK * 2)
#define BK   64
#define CLD  130

#define NBLK      1024           // 4 blocks/CU * 256 CU -- co-resident by construction
#define NB_ROUTER 256            // 4 tokens per block

#define NT_CONV   2304           // per matrix: 8 e * 6 k * 48 n (128k x 64n tiles)
#define NU_FFN1   1152           // 24 mt * 48 nt
#define NU_P1     (NU_FFN1 + NT_CONV)   // 3456, interleaved 1:2
#define KSPLIT    4
#define KSEG      (FF / KSPLIT)  // 768
#define NU_FFN2   (24 * 12 * KSPLIT)    // 1152 (24 mt * 12 n64 * 4 ks)

#define TGT1 (NBLK + 1)          // phase0: all blocks + scatter bonus
#define TGT2 (TGT1 + NBLK)       // phase1

typedef unsigned short u16;
typedef unsigned int   u32;
typedef __bf16 bf16x8 __attribute__((ext_vector_type(8)));
typedef float  f32x4  __attribute__((ext_vector_type(4)));
typedef u16    u16x8  __attribute__((ext_vector_type(8)));

__device__ __forceinline__ u16 f2bf(float f) {
  union { float f; u32 u; } v; v.f = f;
  u32 r = v.u + 0x7FFFu + ((v.u >> 16) & 1u);
  return (u16)(r >> 16);
}

// global->LDS direct DMA, 16B per lane. LDS dest wave-uniform base; HW writes
// base + lane*16. Global address is per-lane (gather OK).
__device__ __forceinline__ void load16(const void* g, void* l) {
  __builtin_amdgcn_global_load_lds(
      (const __attribute__((address_space(1))) u32*)g,
      (__attribute__((address_space(3))) u32*)l, 16, 0, 0);
}

// ---------------------------------------------------------------------------
// Convert one 128k x 64n tile: fp32 [K][N] -> bf16 [N][K]. Register-staged
// (measured-best: R2, 56.5us for w1-half). Each store covers 4 FULL 256B
// row segments (no partial sectors).
// ---------------------------------------------------------------------------
__device__ __forceinline__ void conv_tile(
    const float* __restrict__ src, u16* __restrict__ dst,
    int K, int N, int k0, int n0, u16* lt, int tid, int lane, int wid)
{
  const int rr = tid >> 4;          // k sub-row 0..15
  const int cc = (tid & 15) << 2;   // n 0..60

  const float* s0 = src + (size_t)(k0 + rr) * N + n0 + cc;
  float4 v[8];
#pragma unroll
  for (int j = 0; j < 8; ++j) v[j] = *(const float4*)(s0 + (size_t)j * 16 * N);
  __builtin_amdgcn_sched_barrier(0);   // keep loads clustered

#pragma unroll
  for (int j = 0; j < 8; ++j) {
    const int k = j * 16 + rr;
    lt[(cc + 0) * CLD + k] = f2bf(v[j].x); lt[(cc + 1) * CLD + k] = f2bf(v[j].y);
    lt[(cc + 2) * CLD + k] = f2bf(v[j].z); lt[(cc + 3) * CLD + k] = f2bf(v[j].w);
  }
  __syncthreads();

  const int l15 = lane & 15;
  const int r4  = lane >> 4;
#pragma unroll
  for (int s = 0; s < 4; ++s) {
    const int r = wid * 16 + s * 4 + r4;   // n row 0..63
    u16x8 vv;
#pragma unroll
    for (int d = 0; d < 8; ++d) vv[d] = lt[r * CLD + l15 * 8 + d];
    *(u16x8*)(dst + (size_t)(n0 + r) * K + k0 + l15 * 8) = vv;
  }
}

// expert lookup for capacity grids: mt -> (e, m0); e stays -1 past the end.
__device__ __forceinline__ int find_expert(const int* __restrict__ seg,
                                           int mt, int* m0_out) {
  int e = -1, m0 = 0, off = 0;
#pragma unroll
  for (int ee = 0; ee < NE; ++ee) {
    const int T = (seg[NE + ee] + 127) >> 7;
    if (e < 0 && mt < off + T) { e = ee; m0 = (mt - off) << 7; }
    off += T;
  }
  *m0_out = m0;
  return e;
}

// ---------------------------------------------------------------------------
// ffn1 unit: 128m x 64n, BK=64, 4 waves (2x2 over 64x32, acc 4x2),
// global_load_lds staging, XOR-swizzled unpadded LDS.
// smem: As[128*64] @0, Bs[64*64] @16384, toks[128] @24576.
// ---------------------------------------------------------------------------
__device__ __forceinline__ void ffn1_unit(
    int fid, const u16* __restrict__ xb, const u16* __restrict__ w1t,
    const int* __restrict__ tos, const int* __restrict__ seg,
    u16* __restrict__ hbuf, char* smem, int tid, int lane, int wid)
{
  const int mt = fid / 48, nt = fid % 48;
  int m0;
  const int e = find_expert(seg, mt, &m0);
  if (e < 0) return;
  const int cnt   = seg[NE + e];
  const int start = seg[e];
  const int n0    = nt * 64;

  u16* As   = (u16*)smem;
  u16* Bs   = (u16*)(smem + 16384);
  int* toks = (int*)(smem + 24576);

  if (tid < 128) toks[tid] = tos[start + min(m0 + tid, cnt - 1)];
  __syncthreads();

  const int rsub = lane >> 3;
  const int c8   = (lane & 7) ^ rsub;

  const u16* ag[4]; u16* al[4];
#pragma unroll
  for (int i = 0; i < 4; ++i) {
    const int rb = wid * 8 + i * 32;
    ag[i] = xb + (size_t)toks[rb + rsub] * HD + c8 * 8;
    al[i] = As + rb * 64;
  }
  const u16* bg[2]; u16* bl[2];
#pragma unroll
  for (int i = 0; i < 2; ++i) {
    const int rb = wid * 8 + i * 32;
    bg[i] = w1t + ((size_t)e * FF + n0 + rb + rsub) * HD + c8 * 8;
    bl[i] = Bs + rb * 64;
  }

  const int wm  = (wid >> 1) << 6;
  const int wn  = (wid & 1) << 5;
  const int q   = lane >> 4;
  const int r16 = lane & 15;

  f32x4 acc[4][2] = {};

  for (int k0 = 0; k0 < HD; k0 += BK) {
#pragma unroll
    for (int i = 0; i < 4; ++i) load16(ag[i] + k0, al[i]);
#pragma unroll
    for (int i = 0; i < 2; ++i) load16(bg[i] + k0, bl[i]);
    __syncthreads();
#pragma unroll
    for (int s = 0; s < 2; ++s) {
      const int pa = ((s << 2) + q) ^ (r16 & 7);
      bf16x8 af[4], bf[2];
#pragma unroll
      for (int t = 0; t < 4; ++t)
        af[t] = *(const bf16x8*)(&As[(wm + t * 16 + r16) * 64 + pa * 8]);
#pragma unroll
      for (int t = 0; t < 2; ++t)
        bf[t] = *(const bf16x8*)(&Bs[(wn + t * 16 + r16) * 64 + pa * 8]);
#pragma unroll
      for (int t = 0; t < 4; ++t)
#pragma unroll
        for (int c = 0; c < 2; ++c)
          acc[t][c] = __builtin_amdgcn_mfma_f32_16x16x32_bf16(af[t], bf[c], acc[t][c], 0, 0, 0);
    }
    __syncthreads();
  }

#pragma unroll
  for (int t = 0; t < 4; ++t) {
    const int mbase = m0 + wm + t * 16 + q * 4;
#pragma unroll
    for (int i = 0; i < 4; ++i) {
      if (mbase + i < cnt) {
        u16* drow = hbuf + (size_t)(start + mbase + i) * FF + n0 + wn;
#pragma unroll
        for (int c = 0; c < 2; ++c) {
          float vv = acc[t][c][i];
          vv = 0.5f * vv * (1.0f + erff(vv * 0.70710678118f));
          drow[c * 16 + r16] = f2bf(vv);
        }
      }
    }
  }
}

// ---------------------------------------------------------------------------
// ffn2 unit: 128m x 64n, K-split x4, atomic fp32 accumulate into out.
// smem: As @0, Bs @16384, toks @24576, gates @25088.
// ---------------------------------------------------------------------------
__device__ __forceinline__ void ffn2_unit(
    int u, const u16* __restrict__ hbuf, const u16* __restrict__ w2t,
    const int* __restrict__ tos, const float* __restrict__ gos,
    const int* __restrict__ seg, float* __restrict__ out,
    char* smem, int tid, int lane, int wid)
{
  const int mt   = u / 48;
  const int rest = u % 48;
  const int n0   = (rest >> 2) * 64;   // 12 n-tiles
  const int ks   = rest & 3;
  int m0;
  const int e = find_expert(seg, mt, &m0);
  if (e < 0) return;
  const int cnt   = seg[NE + e];
  const int start = seg[e];
  const int kbase = ks * KSEG;

  u16*   As    = (u16*)smem;
  u16*   Bs    = (u16*)(smem + 16384);
  int*   toks  = (int*)(smem + 24576);
  float* gates = (float*)(smem + 25088);

  if (tid < 128) {
    const int idx = start + min(m0 + tid, cnt - 1);
    toks[tid]  = tos[idx];
    gates[tid] = gos[idx];
  }
  __syncthreads();

  const int rsub = lane >> 3;
  const int c8   = (lane & 7) ^ rsub;

  const u16* ag[4]; u16* al[4];
#pragma unroll
  for (int i = 0; i < 4; ++i) {
    const int rb = wid * 8 + i * 32;
    ag[i] = hbuf + (size_t)(start + min(m0 + rb + rsub, cnt - 1)) * FF + kbase + c8 * 8;
    al[i] = As + rb * 64;
  }
  const u16* bg[2]; u16* bl[2];
#pragma unroll
  for (int i = 0; i < 2; ++i) {
    const int rb = wid * 8 + i * 32;
    bg[i] = w2t + ((size_t)e * HD + n0 + rb + rsub) * FF + kbase + c8 * 8;
    bl[i] = Bs + rb * 64;
  }

  const int wm  = (wid >> 1) << 6;
  const int wn  = (wid & 1) << 5;
  const int q   = lane >> 4;
  const int r16 = lane & 15;

  f32x4 acc[4][2] = {};

  for (int k0 = 0; k0 < KSEG; k0 += BK) {
#pragma unroll
    for (int i = 0; i < 4; ++i) load16(ag[i] + k0, al[i]);
#pragma unroll
    for (int i = 0; i < 2; ++i) load16(bg[i] + k0, bl[i]);
    __syncthreads();
#pragma unroll
    for (int s = 0; s < 2; ++s) {
      const int pa = ((s << 2) + q) ^ (r16 & 7);
      bf16x8 af[4], bf[2];
#pragma unroll
      for (int t = 0; t < 4; ++t)
        af[t] = *(const bf16x8*)(&As[(wm + t * 16 + r16) * 64 + pa * 8]);
#pragma unroll
      for (int t = 0; t < 2; ++t)
        bf[t] = *(const bf16x8*)(&Bs[(wn + t * 16 + r16) * 64 + pa * 8]);
#pragma unroll
      for (int t = 0; t < 4; ++t)
#pragma unroll
        for (int c = 0; c < 2; ++c)
          acc[t][c] = __builtin_amdgcn_mfma_f32_16x16x32_bf16(af[t], bf[c], acc[t][c], 0, 0, 0);
    }
    __syncthreads();
  }

#pragma unroll
  for (int t = 0; t < 4; ++t) {
    const int mbase = wm + t * 16 + q * 4;
#pragma unroll
    for (int i = 0; i < 4; ++i) {
      const int mloc = mbase + i;
      if (m0 + mloc < cnt) {
        const int tok  = toks[mloc];
        const float gv = gates[mloc];
        float* drow = out + (size_t)tok * HD + n0 + wn;
#pragma unroll
        for (int c = 0; c < 2; ++c)
          atomicAdd(drow + c * 16 + r16, gv * acc[t][c][i]);
      }
    }
  }
}

// device-wide arrive-and-spin barrier (all NBLK blocks co-resident).
__device__ __forceinline__ void grid_bar(int* bar, int target) {
  __syncthreads();
  if (threadIdx.x == 0) {
    __threadfence();
    __hip_atomic_fetch_add(bar, 1, __ATOMIC_RELEASE, __HIP_MEMORY_SCOPE_AGENT);
    while (__hip_atomic_load(bar, __ATOMIC_ACQUIRE, __HIP_MEMORY_SCOPE_AGENT) < target)
      __builtin_amdgcn_s_sleep(2);
  }
  __syncthreads();
  __threadfence();
}

// ---------------------------------------------------------------------------
// Persistent kernel: grid = 1024 blocks = exactly 4 blocks/CU
// (launch_bounds(256,4): VGPR<=128, LDS 25.6KB*4=102KB<160KB -> co-resident).
// P0: router + w1 convert + out-zero + in-kernel scatter.
// P1: ffn1 (1152 units) interleaved 1:2 with w2 convert (2304 tiles).
// P2: ffn2 (1152 units).
// ---------------------------------------------------------------------------
__global__ __launch_bounds__(256, 4) void moe_persistent(
    const float* __restrict__ w1, const float* __restrict__ w2,
    u16* __restrict__ w1t, u16* __restrict__ w2t,
    const float* __restrict__ x, const float* __restrict__ rw,
    u16* __restrict__ xb, int* __restrict__ ti, float* __restrict__ tg,
    int* __restrict__ tos, float* __restrict__ gos, int* __restrict__ seg,
    int* __restrict__ ctr, u16* __restrict__ hbuf, float* __restrict__ out)
{
  __shared__ __align__(16) char smem[25600];
  __shared__ int soff[NE], scnt[NE], spos[NE], lastFlag;
  const int tid  = threadIdx.x;
  const int lane = tid & 63;
  const int wid  = tid >> 6;
  const int bid  = blockIdx.x;
  int* bar = &ctr[0];

  // ================= PHASE 0 =================
  // zero a 3KB slice of out (replaces hipMemsetAsync(d_out))
  {
    float4* o4 = (float4*)out;
    const float4 zz = {0.f, 0.f, 0.f, 0.f};
    if (tid < 192) o4[(size_t)bid * 192 + tid] = zz;
  }

  if (bid < NB_ROUTER) {
    // ---- router: logits + top2 for 4 tokens (one per wave) ----
    const int t = bid * 4 + wid;
    const float* xrow = x + (size_t)t * HD;
    u16* xbrow = xb + (size_t)t * HD;

    float acc[NE] = {};
#pragma unroll
    for (int j = 0; j < 12; ++j) {
      const int h = lane + j * 64;
      const float xv = xrow[h];
      xbrow[h] = f2bf(xv);
      const float4 r0 = *(const float4*)(rw + h * 8);
      const float4 r1 = *(const float4*)(rw + h * 8 + 4);
      acc[0] += xv * r0.x; acc[1] += xv * r0.y;
      acc[2] += xv * r0.z; acc[3] += xv * r0.w;
      acc[4] += xv * r1.x; acc[5] += xv * r1.y;
      acc[6] += xv * r1.z; acc[7] += xv * r1.w;
    }
#pragma unroll
    for (int e = 0; e < NE; ++e) {
      float v = acc[e];
#pragma unroll
      for (int off = 32; off; off >>= 1) v += __shfl_down(v, off, 64);
      acc[e] = v;
    }
    if (lane == 0) {
      float v0 = -1e30f, v1 = -1e30f; int i0 = 0, i1 = 0;
#pragma unroll
      for (int e = 0; e < NE; ++e) {
        const float p = acc[e];
        if (p > v0) { v1 = v0; i1 = i0; v0 = p; i0 = e; }
        else if (p > v1) { v1 = p; i1 = e; }
      }
      const float e1 = expf(v1 - v0);
      ti[2 * t] = i0;      ti[2 * t + 1] = i1;
      tg[2 * t] = 1.0f / (1.0f + e1);
      tg[2 * t + 1] = e1 / (1.0f + e1);
    }

    // ---- completion counter; last router block scatters (validated R3) ----
    __syncthreads();
    __threadfence();
    if (tid == 0) lastFlag = (atomicAdd(&ctr[1], 1) == NB_ROUTER - 1);
    __syncthreads();
    if (lastFlag) {
      __threadfence();   // acquire: all routers' ti/tg
      if (tid < NE) scnt[tid] = 0;
      __syncthreads();
      int mye[8]; float myg[8];
#pragma unroll
      for (int j = 0; j < 8; ++j) {
        const int s = tid * 8 + j;
        mye[j] = ti[s]; myg[j] = tg[s];
        atomicAdd(&scnt[mye[j]], 1);
      }
      __syncthreads();
      if (tid == 0) {
        int o = 0;
        for (int e = 0; e < NE; ++e) {
          soff[e] = o; seg[e] = o; seg[NE + e] = scnt[e]; o += scnt[e];
        }
      }
      if (tid < NE) spos[tid] = 0;
      __syncthreads();
#pragma unroll
      for (int j = 0; j < 8; ++j) {
        const int s = tid * 8 + j;
        const int p = atomicAdd(&spos[mye[j]], 1);
        const int o = soff[mye[j]] + p;
        tos[o] = s >> 1;
        gos[o] = myg[j];
      }
      __syncthreads();
      __threadfence();   // release scatter outputs
      if (tid == 0)
        __hip_atomic_fetch_add(bar, 1, __ATOMIC_RELEASE, __HIP_MEMORY_SCOPE_AGENT);
    }
  }

  // ---- w1 convert: 2304 tiles; router blocks get 2, bids>=768 get 3 ----
  {
    u16* lt = (u16*)smem;
    {
      const int cid = bid;                       // 0..1023
      __syncthreads();
      conv_tile(w1 + (size_t)(cid / 288) * HD * FF,
                w1t + (size_t)(cid / 288) * FF * HD, HD, FF,
                ((cid % 288) / 48) * 128, ((cid % 288) % 48) * 64,
                lt, tid, lane, wid);
    }
    {
      const int cid = bid + 1024;                // 1024..2047
      __syncthreads();
      conv_tile(w1 + (size_t)(cid / 288) * HD * FF,
                w1t + (size_t)(cid / 288) * FF * HD, HD, FF,
                ((cid % 288) / 48) * 128, ((cid % 288) % 48) * 64,
                lt, tid, lane, wid);
    }
    if (bid >= 768) {
      const int cid = 2048 + (bid - 768);        // 2048..2303
      __syncthreads();
      conv_tile(w1 + (size_t)(cid / 288) * HD * FF,
                w1t + (size_t)(cid / 288) * FF * HD, HD, FF,
                ((cid % 288) / 48) * 128, ((cid % 288) % 48) * 64,
                lt, tid, lane, wid);
    }
  }

  grid_bar(bar, TGT1);

  // ================= PHASE 1: ffn1 (1:) + w2 convert (:2) =================
  for (int u = bid; u < NU_P1; u += NBLK) {
    __syncthreads();
    if (u % 3 == 0) {
      ffn1_unit(u / 3, xb, w1t, tos, seg, hbuf, smem, tid, lane, wid);
    } else {
      const int cid = u - u / 3 - 1;             // 0..2303
      const int z   = cid / 288;
      const int rem = cid % 288;
      conv_tile(w2 + (size_t)z * FF * HD, w2t + (size_t)z * HD * FF,
                FF, HD, (rem % 24) * 128, (rem / 24) * 64,
                (u16*)smem, tid, lane, wid);
    }
  }

  grid_bar(bar, TGT2);

  // ================= PHASE 2: ffn2 =================
  for (int u = bid; u < NU_FFN2; u += NBLK) {
    __syncthreads();
    ffn2_unit(u, hbuf, w2t, tos, gos, seg, out, smem, tid, lane, wid);
  }
}

// ---------------------------------------------------------------------------
extern "C" void kernel_launch(void* const* d_in, const int* in_sizes, int n_in,
                              void* d_out, int out_size, void* d_ws, size_t ws_size,
                              hipStream_t stream) {
  const float* x  = (const float*)d_in[0];
  const float* rw = (const float*)d_in[1];
  const float* w1 = (const float*)d_in[2];
  const float* w2 = (const float*)d_in[3];
  float* out = (float*)d_out;

  char* ws = (char*)d_ws;
  const size_t o_xb    = 0;
  const size_t o_hbuf  = o_xb + (size_t)NTOK * HD * 2;
  const size_t o_tos   = o_hbuf + (size_t)NSLOT * FF * 2;
  const size_t o_gos   = o_tos + (size_t)NSLOT * 4;
  const size_t o_seg   = o_gos + (size_t)NSLOT * 4;
  const size_t o_ctr   = o_seg + 64 * 4;
  const size_t o_ti    = o_ctr + 64;
  const size_t o_tg    = o_ti + (size_t)NSLOT * 4;
  const size_t o_w1t   = (o_tg + (size_t)NSLOT * 4 + 255) & ~(size_t)255;
  const size_t o_w2t   = o_w1t + (size_t)NE * HD * FF * 2;
  u16*   xb    = (u16*)(ws + o_xb);
  u16*   hbuf  = (u16*)(ws + o_hbuf);
  int*   tos   = (int*)(ws + o_tos);
  float* gos   = (float*)(ws + o_gos);
  int*   seg   = (int*)(ws + o_seg);
  int*   ctr   = (int*)(ws + o_ctr);
  int*   ti    = (int*)(ws + o_ti);
  float* tg    = (float*)(ws + o_tg);
  u16*   w1t   = (u16*)(ws + o_w1t);
  u16*   w2t   = (u16*)(ws + o_w2t);

  hipMemsetAsync(ctr, 0, 64, stream);
  hipLaunchKernelGGL(moe_persistent, dim3(NBLK), dim3(256), 0, stream,
                     w1, w2, w1t, w2t, x, rw, xb, ti, tg, tos, gos, seg,
                     ctr, hbuf, out);
}

// Round 5
// 265.975 us; speedup vs baseline: 3.0010x; 3.0010x over previous
//
#include <hip/hip_runtime.h>
#include <cmath>

#define NTOK 1024
#define HD   768
#define FF   3072
#define NE   8
#define NSLOT (NTOK * 2)
#define BK   64

#define NB_ROUTER 256            // 4 tokens per block
#define NU_FFN1   1152           // 24 mt capacity * 48 nt
#define KSPLIT    4
#define KSEG      (FF / KSPLIT)  // 768
#define NU_FFN2   1152           // 24 mt * 12 n64 * 4 ks

typedef unsigned short u16;
typedef unsigned int   u32;
typedef __bf16 bf16x8 __attribute__((ext_vector_type(8)));
typedef float  f32x4  __attribute__((ext_vector_type(4)));
typedef u16    u16x8  __attribute__((ext_vector_type(8)));

__device__ __forceinline__ u16 f2bf(float f) {
  union { float f; u32 u; } v; v.f = f;
  u32 r = v.u + 0x7FFFu + ((v.u >> 16) & 1u);
  return (u16)(r >> 16);
}

// global->LDS direct DMA, 16B per lane. LDS dest wave-uniform base; HW writes
// base + lane*16. Global address is per-lane (gather OK). Zero VGPR cost.
__device__ __forceinline__ void load16(const void* g, void* l) {
  __builtin_amdgcn_global_load_lds(
      (const __attribute__((address_space(1))) u32*)g,
      (__attribute__((address_space(3))) u32*)l, 16, 0, 0);
}

// expert lookup for capacity grids: mt -> (e, m0); e stays -1 past the end.
__device__ __forceinline__ int find_expert(const int* __restrict__ seg,
                                           int mt, int* m0_out) {
  int e = -1, m0 = 0, off = 0;
#pragma unroll
  for (int ee = 0; ee < NE; ++ee) {
    const int T = (seg[NE + ee] + 127) >> 7;
    if (e < 0 && mt < off + T) { e = ee; m0 = (mt - off) << 7; }
    off += T;
  }
  *m0_out = m0;
  return e;
}

// ---------------------------------------------------------------------------
// K1: router (256 blocks). Zeroes `out`, computes logits+top2 for 4 tokens
// per block, writes bf16 token rows; LAST block to finish runs the scatter
// (validated pattern R3/R4). ctr[1] is the completion counter (host memset).
// ---------------------------------------------------------------------------
__global__ __launch_bounds__(256) void router_kernel(
    const float* __restrict__ x, const float* __restrict__ rw,
    u16* __restrict__ xb, int* __restrict__ ti, float* __restrict__ tg,
    int* __restrict__ tos, float* __restrict__ gos, int* __restrict__ seg,
    int* __restrict__ ctr, float* __restrict__ out)
{
  __shared__ int soff[NE], scnt[NE], spos[NE], lastFlag;
  const int tid  = threadIdx.x;
  const int lane = tid & 63;
  const int wid  = tid >> 6;
  const int bid  = blockIdx.x;

  // zero a 12KB slice of out (replaces hipMemsetAsync(d_out))
  {
    float4* o4 = (float4*)out;
    const float4 zz = {0.f, 0.f, 0.f, 0.f};
#pragma unroll
    for (int i = 0; i < 3; ++i) o4[(size_t)bid * 768 + i * 256 + tid] = zz;
  }

  // ---- router: logits + top2 for 4 tokens (one per wave) ----
  const int t = bid * 4 + wid;
  const float* xrow = x + (size_t)t * HD;
  u16* xbrow = xb + (size_t)t * HD;

  float acc[NE] = {};
#pragma unroll
  for (int j = 0; j < 12; ++j) {
    const int h = lane + j * 64;
    const float xv = xrow[h];
    xbrow[h] = f2bf(xv);
    const float4 r0 = *(const float4*)(rw + h * 8);
    const float4 r1 = *(const float4*)(rw + h * 8 + 4);
    acc[0] += xv * r0.x; acc[1] += xv * r0.y;
    acc[2] += xv * r0.z; acc[3] += xv * r0.w;
    acc[4] += xv * r1.x; acc[5] += xv * r1.y;
    acc[6] += xv * r1.z; acc[7] += xv * r1.w;
  }
#pragma unroll
  for (int e = 0; e < NE; ++e) {
    float v = acc[e];
#pragma unroll
    for (int off = 32; off; off >>= 1) v += __shfl_down(v, off, 64);
    acc[e] = v;
  }
  if (lane == 0) {
    float v0 = -1e30f, v1 = -1e30f; int i0 = 0, i1 = 0;
#pragma unroll
    for (int e = 0; e < NE; ++e) {
      const float p = acc[e];
      if (p > v0) { v1 = v0; i1 = i0; v0 = p; i0 = e; }
      else if (p > v1) { v1 = p; i1 = e; }
    }
    const float e1 = expf(v1 - v0);
    ti[2 * t] = i0;      ti[2 * t + 1] = i1;
    tg[2 * t] = 1.0f / (1.0f + e1);
    tg[2 * t + 1] = e1 / (1.0f + e1);
  }

  // ---- completion counter; last block scatters ----
  __syncthreads();
  __threadfence();
  if (tid == 0) lastFlag = (atomicAdd(&ctr[1], 1) == NB_ROUTER - 1);
  __syncthreads();
  if (!lastFlag) return;
  __threadfence();   // acquire: all routers' ti/tg

  if (tid < NE) scnt[tid] = 0;
  __syncthreads();
  int mye[8]; float myg[8];
#pragma unroll
  for (int j = 0; j < 8; ++j) {
    const int s = tid * 8 + j;
    mye[j] = ti[s]; myg[j] = tg[s];
    atomicAdd(&scnt[mye[j]], 1);
  }
  __syncthreads();
  if (tid == 0) {
    int o = 0;
    for (int e = 0; e < NE; ++e) {
      soff[e] = o; seg[e] = o; seg[NE + e] = scnt[e]; o += scnt[e];
    }
    ctr[1] = 0;   // self-reset for next graph replay (memset still covers run 1)
  }
  if (tid < NE) spos[tid] = 0;
  __syncthreads();
#pragma unroll
  for (int j = 0; j < 8; ++j) {
    const int s = tid * 8 + j;
    const int p = atomicAdd(&spos[mye[j]], 1);
    const int o = soff[mye[j]] + p;
    tos[o] = s >> 1;
    gos[o] = myg[j];
  }
}

// ---------------------------------------------------------------------------
// FFN GEMM with in-loop B transpose+convert (NO separate weight conversion).
// 128m x 64n tile, BK=64, 4 waves (2x2 over 64x32, acc 4x2).
// A: bf16 via load16 DMA (XOR-swizzled via pre-swizzled global source).
// B: fp32 w[k][n] reg-staged (4x float4/thread, coalesced), f2bf, written
//    TRANSPOSED into swizzled Bs[n][k] as 4x ds_write_b64 (thread owns
//    4 consecutive k at 4 n's -> 8B k-contiguous writes).
// B(k+1) regs prefetched before the MFMA phase; the pre-barrier vmcnt(0)
// drain lands after MFMA, so global latency hides under compute.
// ---------------------------------------------------------------------------

// stage-B geometry (per thread): rr=tid>>4 (k-quad 0..15), cc=(tid&15)*4 (n)
#define LOADB(BSRC, BN, K0, D) do {                                          \
  _Pragma("unroll")                                                          \
  for (int j = 0; j < 4; ++j)                                                \
    D[j] = *(const f32x4*)((BSRC) + (size_t)((K0) + rr * 4 + j) * (BN));     \
} while (0)

#define WRITEB(D) do {                                                       \
  _Pragma("unroll")                                                          \
  for (int i = 0; i < 4; ++i) {                                              \
    uint2 w;                                                                 \
    w.x = (u32)f2bf(D[0][i]) | ((u32)f2bf(D[1][i]) << 16);                   \
    w.y = (u32)f2bf(D[2][i]) | ((u32)f2bf(D[3][i]) << 16);                   \
    *(uint2*)(&Bs[wofs[i]]) = w;                                             \
  }                                                                          \
} while (0)

// FFN1: h = gelu(x_gather @ w1[e]) -> hbuf (bf16)
__global__ __launch_bounds__(256) void ffn1_kernel(
    const u16* __restrict__ xb, const float* __restrict__ w1,
    const int* __restrict__ tos, const int* __restrict__ seg,
    u16* __restrict__ hbuf)
{
  const int fid = blockIdx.x;
  const int mt = fid / 48, nt = fid % 48;
  int m0;
  const int e = find_expert(seg, mt, &m0);
  if (e < 0) return;
  const int cnt   = seg[NE + e];
  const int start = seg[e];
  const int n0    = nt * 64;
  const float* w1e = w1 + (size_t)e * HD * FF;

  __shared__ __align__(16) u16 As[128 * 64];
  __shared__ __align__(16) u16 Bs[64 * 64];
  __shared__ int toks[128];

  const int tid = threadIdx.x;
  if (tid < 128) toks[tid] = tos[start + min(m0 + tid, cnt - 1)];
  __syncthreads();

  const int lane = tid & 63;
  const int wid  = tid >> 6;
  const int rsub = lane >> 3;
  const int c8   = (lane & 7) ^ rsub;

  const u16* ag[4]; u16* al[4];
#pragma unroll
  for (int i = 0; i < 4; ++i) {
    const int rb = wid * 8 + i * 32;
    ag[i] = xb + (size_t)toks[rb + rsub] * HD + c8 * 8;
    al[i] = As + rb * 64;
  }

  // B-stage addressing
  const int rr = tid >> 4;
  const int cc = (tid & 15) << 2;
  const float* bsrc = w1e + n0 + cc;
  int wofs[4];
#pragma unroll
  for (int i = 0; i < 4; ++i) {
    const int n = cc + i;
    wofs[i] = n * 64 + (((rr >> 1) ^ (n & 7)) << 3) + ((rr & 1) << 2);
  }

  const int wm  = (wid >> 1) << 6;
  const int wn  = (wid & 1) << 5;
  const int q   = lane >> 4;
  const int r16 = lane & 15;

  f32x4 acc[4][2] = {};
  f32x4 breg[2][4];

  LOADB(bsrc, FF, 0, breg[0]);
#pragma unroll
  for (int kk = 0; kk < 12; ++kk) {
    const int k0 = kk * BK;
#pragma unroll
    for (int i = 0; i < 4; ++i) load16(ag[i] + k0, al[i]);
    WRITEB(breg[kk & 1]);
    __syncthreads();
    if (kk < 11) {
      LOADB(bsrc, FF, k0 + BK, breg[(kk + 1) & 1]);
      __builtin_amdgcn_sched_barrier(0);   // issue prefetch before MFMA
    }
#pragma unroll
    for (int s = 0; s < 2; ++s) {
      const int pa = ((s << 2) + q) ^ (r16 & 7);
      bf16x8 af[4], bf[2];
#pragma unroll
      for (int t = 0; t < 4; ++t)
        af[t] = *(const bf16x8*)(&As[(wm + t * 16 + r16) * 64 + pa * 8]);
#pragma unroll
      for (int t = 0; t < 2; ++t)
        bf[t] = *(const bf16x8*)(&Bs[(wn + t * 16 + r16) * 64 + pa * 8]);
#pragma unroll
      for (int t = 0; t < 4; ++t)
#pragma unroll
        for (int c = 0; c < 2; ++c)
          acc[t][c] = __builtin_amdgcn_mfma_f32_16x16x32_bf16(af[t], bf[c], acc[t][c], 0, 0, 0);
    }
    __syncthreads();
  }

#pragma unroll
  for (int t = 0; t < 4; ++t) {
    const int mbase = m0 + wm + t * 16 + q * 4;
#pragma unroll
    for (int i = 0; i < 4; ++i) {
      if (mbase + i < cnt) {
        u16* drow = hbuf + (size_t)(start + mbase + i) * FF + n0 + wn;
#pragma unroll
        for (int c = 0; c < 2; ++c) {
          float vv = acc[t][c][i];
          vv = 0.5f * vv * (1.0f + erff(vv * 0.70710678118f));
          drow[c * 16 + r16] = f2bf(vv);
        }
      }
    }
  }
}

// FFN2: out += gate * (h @ w2[e]), K-split x4, atomic fp32 accumulate.
__global__ __launch_bounds__(256) void ffn2_kernel(
    const u16* __restrict__ hbuf, const float* __restrict__ w2,
    const int* __restrict__ tos, const float* __restrict__ gos,
    const int* __restrict__ seg, float* __restrict__ out)
{
  const int u    = blockIdx.x;
  const int mt   = u / 48;
  const int rest = u % 48;
  const int n0   = (rest >> 2) * 64;   // 12 n-tiles
  const int ks   = rest & 3;
  int m0;
  const int e = find_expert(seg, mt, &m0);
  if (e < 0) return;
  const int cnt   = seg[NE + e];
  const int start = seg[e];
  const int kbase = ks * KSEG;
  const float* w2e = w2 + (size_t)e * FF * HD;

  __shared__ __align__(16) u16 As[128 * 64];
  __shared__ __align__(16) u16 Bs[64 * 64];
  __shared__ int   toks[128];
  __shared__ float gates[128];

  const int tid = threadIdx.x;
  if (tid < 128) {
    const int idx = start + min(m0 + tid, cnt - 1);
    toks[tid]  = tos[idx];
    gates[tid] = gos[idx];
  }
  __syncthreads();

  const int lane = tid & 63;
  const int wid  = tid >> 6;
  const int rsub = lane >> 3;
  const int c8   = (lane & 7) ^ rsub;

  const u16* ag[4]; u16* al[4];
#pragma unroll
  for (int i = 0; i < 4; ++i) {
    const int rb = wid * 8 + i * 32;
    ag[i] = hbuf + (size_t)(start + min(m0 + rb + rsub, cnt - 1)) * FF + kbase + c8 * 8;
    al[i] = As + rb * 64;
  }

  const int rr = tid >> 4;
  const int cc = (tid & 15) << 2;
  const float* bsrc = w2e + (size_t)kbase * HD + n0 + cc;
  int wofs[4];
#pragma unroll
  for (int i = 0; i < 4; ++i) {
    const int n = cc + i;
    wofs[i] = n * 64 + (((rr >> 1) ^ (n & 7)) << 3) + ((rr & 1) << 2);
  }

  const int wm  = (wid >> 1) << 6;
  const int wn  = (wid & 1) << 5;
  const int q   = lane >> 4;
  const int r16 = lane & 15;

  f32x4 acc[4][2] = {};
  f32x4 breg[2][4];

  LOADB(bsrc, HD, 0, breg[0]);
#pragma unroll
  for (int kk = 0; kk < 12; ++kk) {
    const int k0 = kk * BK;
#pragma unroll
    for (int i = 0; i < 4; ++i) load16(ag[i] + k0, al[i]);
    WRITEB(breg[kk & 1]);
    __syncthreads();
    if (kk < 11) {
      LOADB(bsrc, HD, k0 + BK, breg[(kk + 1) & 1]);
      __builtin_amdgcn_sched_barrier(0);
    }
#pragma unroll
    for (int s = 0; s < 2; ++s) {
      const int pa = ((s << 2) + q) ^ (r16 & 7);
      bf16x8 af[4], bf[2];
#pragma unroll
      for (int t = 0; t < 4; ++t)
        af[t] = *(const bf16x8*)(&As[(wm + t * 16 + r16) * 64 + pa * 8]);
#pragma unroll
      for (int t = 0; t < 2; ++t)
        bf[t] = *(const bf16x8*)(&Bs[(wn + t * 16 + r16) * 64 + pa * 8]);
#pragma unroll
      for (int t = 0; t < 4; ++t)
#pragma unroll
        for (int c = 0; c < 2; ++c)
          acc[t][c] = __builtin_amdgcn_mfma_f32_16x16x32_bf16(af[t], bf[c], acc[t][c], 0, 0, 0);
    }
    __syncthreads();
  }

#pragma unroll
  for (int t = 0; t < 4; ++t) {
    const int mbase = wm + t * 16 + q * 4;
#pragma unroll
    for (int i = 0; i < 4; ++i) {
      const int mloc = mbase + i;
      if (m0 + mloc < cnt) {
        const int tok  = toks[mloc];
        const float gv = gates[mloc];
        float* drow = out + (size_t)tok * HD + n0 + wn;
#pragma unroll
        for (int c = 0; c < 2; ++c)
          atomicAdd(drow + c * 16 + r16, gv * acc[t][c][i]);
      }
    }
  }
}

// ---------------------------------------------------------------------------
extern "C" void kernel_launch(void* const* d_in, const int* in_sizes, int n_in,
                              void* d_out, int out_size, void* d_ws, size_t ws_size,
                              hipStream_t stream) {
  const float* x  = (const float*)d_in[0];
  const float* rw = (const float*)d_in[1];
  const float* w1 = (const float*)d_in[2];
  const float* w2 = (const float*)d_in[3];
  float* out = (float*)d_out;

  char* ws = (char*)d_ws;
  const size_t o_xb    = 0;
  const size_t o_hbuf  = o_xb + (size_t)NTOK * HD * 2;
  const size_t o_tos   = o_hbuf + (size_t)NSLOT * FF * 2;
  const size_t o_gos   = o_tos + (size_t)NSLOT * 4;
  const size_t o_seg   = o_gos + (size_t)NSLOT * 4;
  const size_t o_ctr   = o_seg + 64 * 4;
  const size_t o_ti    = o_ctr + 64;
  const size_t o_tg    = o_ti + (size_t)NSLOT * 4;
  u16*   xb    = (u16*)(ws + o_xb);
  u16*   hbuf  = (u16*)(ws + o_hbuf);
  int*   tos   = (int*)(ws + o_tos);
  float* gos   = (float*)(ws + o_gos);
  int*   seg   = (int*)(ws + o_seg);
  int*   ctr   = (int*)(ws + o_ctr);
  int*   ti    = (int*)(ws + o_ti);
  float* tg    = (float*)(ws + o_tg);

  hipMemsetAsync(ctr, 0, 64, stream);
  hipLaunchKernelGGL(router_kernel, dim3(NB_ROUTER), dim3(256), 0, stream,
                     x, rw, xb, ti, tg, tos, gos, seg, ctr, out);
  hipLaunchKernelGGL(ffn1_kernel, dim3(NU_FFN1), dim3(256), 0, stream,
                     xb, w1, tos, seg, hbuf);
  hipLaunchKernelGGL(ffn2_kernel, dim3(NU_FFN2), dim3(256), 0, stream,
                     hbuf, w2, tos, gos, seg, out);
}

// Round 8
// 255.792 us; speedup vs baseline: 3.1205x; 1.0398x over previous
//
// moe v7 (r6 design, resubmit build r7b)
#include <hip/hip_runtime.h>
#include <cmath>

#define NTOK 1024
#define HD   768
#define FF   3072
#define NE   8
#define NSLOT (NTOK * 2)
#define BK   64

#define NB_ROUTER 256            // 4 tokens per block
#define NU_MT     39             // max sum ceil(cnt_e/64) = 32 + 7
#define NU_FFN1   (NU_MT * 48)   // 1872
#define KSPLIT    4
#define KSEG      (FF / KSPLIT)  // 768
#define NU_FFN2   (NU_MT * 12 * KSPLIT)  // 1872

typedef unsigned short u16;
typedef unsigned int   u32;
typedef __bf16 bf16x8 __attribute__((ext_vector_type(8)));
typedef float  f32x4  __attribute__((ext_vector_type(4)));
typedef u16    u16x8  __attribute__((ext_vector_type(8)));

__device__ __forceinline__ u16 f2bf(float f) {
  union { float f; u32 u; } v; v.f = f;
  u32 r = v.u + 0x7FFFu + ((v.u >> 16) & 1u);
  return (u16)(r >> 16);
}

// global->LDS direct DMA, 16B per lane. LDS dest wave-uniform base; HW writes
// base + lane*16. Global address is per-lane (gather OK). Zero VGPR cost.
__device__ __forceinline__ void load16(const void* g, void* l) {
  __builtin_amdgcn_global_load_lds(
      (const __attribute__((address_space(1))) u32*)g,
      (__attribute__((address_space(3))) u32*)l, 16, 0, 0);
}

// expert lookup for capacity grids (64-row tiles): mt -> (e, m0); -1 past end.
// note: empty experts contribute 0 tiles, so e>=0 implies cnt>=1.
__device__ __forceinline__ int find_expert(const int* __restrict__ seg,
                                           int mt, int* m0_out) {
  int e = -1, m0 = 0, off = 0;
#pragma unroll
  for (int ee = 0; ee < NE; ++ee) {
    const int T = (seg[NE + ee] + 63) >> 6;
    if (e < 0 && mt < off + T) { e = ee; m0 = (mt - off) << 6; }
    off += T;
  }
  *m0_out = m0;
  return e;
}

// ---------------------------------------------------------------------------
// K1: router (256 blocks). Zeroes `out`, computes logits+top2 for 4 tokens
// per block, writes bf16 token rows; LAST block to finish runs the scatter.
// (completion-counter pattern validated R3/R5; all barriers block-uniform.)
// ---------------------------------------------------------------------------
__global__ __launch_bounds__(256) void router_kernel(
    const float* __restrict__ x, const float* __restrict__ rw,
    u16* __restrict__ xb, int* __restrict__ ti, float* __restrict__ tg,
    int* __restrict__ tos, float* __restrict__ gos, int* __restrict__ seg,
    int* __restrict__ ctr, float* __restrict__ out)
{
  __shared__ int soff[NE], scnt[NE], spos[NE], lastFlag;
  const int tid  = threadIdx.x;
  const int lane = tid & 63;
  const int wid  = tid >> 6;
  const int bid  = blockIdx.x;

  // zero a 12KB slice of out (replaces hipMemsetAsync(d_out))
  {
    float4* o4 = (float4*)out;
    const float4 zz = {0.f, 0.f, 0.f, 0.f};
#pragma unroll
    for (int i = 0; i < 3; ++i) o4[(size_t)bid * 768 + i * 256 + tid] = zz;
  }

  // ---- router: logits + top2 for 4 tokens (one per wave) ----
  const int t = bid * 4 + wid;
  const float* xrow = x + (size_t)t * HD;
  u16* xbrow = xb + (size_t)t * HD;

  float acc[NE] = {};
#pragma unroll
  for (int j = 0; j < 12; ++j) {
    const int h = lane + j * 64;
    const float xv = xrow[h];
    xbrow[h] = f2bf(xv);
    const float4 r0 = *(const float4*)(rw + h * 8);
    const float4 r1 = *(const float4*)(rw + h * 8 + 4);
    acc[0] += xv * r0.x; acc[1] += xv * r0.y;
    acc[2] += xv * r0.z; acc[3] += xv * r0.w;
    acc[4] += xv * r1.x; acc[5] += xv * r1.y;
    acc[6] += xv * r1.z; acc[7] += xv * r1.w;
  }
#pragma unroll
  for (int e = 0; e < NE; ++e) {
    float v = acc[e];
#pragma unroll
    for (int off = 32; off; off >>= 1) v += __shfl_down(v, off, 64);
    acc[e] = v;
  }
  if (lane == 0) {
    float v0 = -1e30f, v1 = -1e30f; int i0 = 0, i1 = 0;
#pragma unroll
    for (int e = 0; e < NE; ++e) {
      const float p = acc[e];
      if (p > v0) { v1 = v0; i1 = i0; v0 = p; i0 = e; }
      else if (p > v1) { v1 = p; i1 = e; }
    }
    const float e1 = expf(v1 - v0);
    ti[2 * t] = i0;      ti[2 * t + 1] = i1;
    tg[2 * t] = 1.0f / (1.0f + e1);
    tg[2 * t + 1] = e1 / (1.0f + e1);
  }

  // ---- completion counter; last block scatters ----
  __syncthreads();
  __threadfence();
  if (tid == 0) lastFlag = (atomicAdd(&ctr[1], 1) == NB_ROUTER - 1);
  __syncthreads();
  if (!lastFlag) return;
  __threadfence();   // acquire: all routers' ti/tg

  if (tid < NE) scnt[tid] = 0;
  __syncthreads();
  int mye[8]; float myg[8];
#pragma unroll
  for (int j = 0; j < 8; ++j) {
    const int s = tid * 8 + j;
    mye[j] = ti[s]; myg[j] = tg[s];
    atomicAdd(&scnt[mye[j]], 1);
  }
  __syncthreads();
  if (tid == 0) {
    int o = 0;
    for (int e = 0; e < NE; ++e) {
      soff[e] = o; seg[e] = o; seg[NE + e] = scnt[e]; o += scnt[e];
    }
    ctr[1] = 0;   // self-reset for next replay
  }
  if (tid < NE) spos[tid] = 0;
  __syncthreads();
#pragma unroll
  for (int j = 0; j < 8; ++j) {
    const int s = tid * 8 + j;
    const int p = atomicAdd(&spos[mye[j]], 1);
    const int o = soff[mye[j]] + p;
    tos[o] = s >> 1;
    gos[o] = myg[j];
  }
}

// ---------------------------------------------------------------------------
// FFN GEMM: 64m x 64n tile, BK=64, 4 waves (2x2 over 32x32, acc 2x2).
// Single-sync pipelined K-loop, double-buffered LDS:
//   step kk: LOADB(k+2) issued FIRST (max distance to the barrier drain),
//            A-DMA(k+1) -> As[nxt], WRITEB regs(k+1) -> Bs[nxt],
//            MFMA on [cur], ONE __syncthreads.
// B staging: thread owns 8 consecutive k x 2 n (rr2=tid>>5, np=tid&31),
//   8x coalesced float2 loads; two b128 LDS writes at phys chunk
//   rr2 ^ (np&7)  (swizzle c ^ ((n>>1)&7)) -> uniform over all 32 banks.
//   Read: cb = ((s<<2)+q) ^ ((r16>>1)&7) -> 2-way max (free).
// A staging: load16 DMA, swizzle c ^ (row&7) via pre-swizzled global source.
// ---------------------------------------------------------------------------

#define LOADB(SRC, LDN, K0, B) do {                                          \
  _Pragma("unroll")                                                          \
  for (int j = 0; j < 8; ++j)                                                \
    B[j] = *(const float2*)((SRC) + (size_t)((K0) + rr2 * 8 + j) * (LDN));   \
} while (0)

#define WRITEB(B, DST) do {                                                  \
  u16x8 v0, v1;                                                              \
  _Pragma("unroll")                                                          \
  for (int j = 0; j < 8; ++j) { v0[j] = f2bf(B[j].x); v1[j] = f2bf(B[j].y); }\
  *(u16x8*)((DST) + wof0) = v0;                                              \
  *(u16x8*)((DST) + wof1) = v1;                                              \
} while (0)

#define MFMA_STEP(ACUR, BCUR) do {                                           \
  _Pragma("unroll")                                                          \
  for (int s = 0; s < 2; ++s) {                                              \
    const int ca = ((s << 2) + q) ^ (r16 & 7);                               \
    const int cb = ((s << 2) + q) ^ ((r16 >> 1) & 7);                        \
    bf16x8 af[2], bf[2];                                                     \
    _Pragma("unroll")                                                        \
    for (int t = 0; t < 2; ++t)                                              \
      af[t] = *(const bf16x8*)(&(ACUR)[(wm + t * 16 + r16) * 64 + ca * 8]);  \
    _Pragma("unroll")                                                        \
    for (int c = 0; c < 2; ++c)                                              \
      bf[c] = *(const bf16x8*)(&(BCUR)[(wn + c * 16 + r16) * 64 + cb * 8]);  \
    _Pragma("unroll")                                                        \
    for (int t = 0; t < 2; ++t)                                              \
      _Pragma("unroll")                                                      \
      for (int c = 0; c < 2; ++c)                                            \
        acc[t][c] = __builtin_amdgcn_mfma_f32_16x16x32_bf16(af[t], bf[c],    \
                                                            acc[t][c], 0, 0, 0); \
  }                                                                          \
} while (0)

// FFN1: h = gelu(x_gather @ w1[e]) -> hbuf (bf16). NSTEP = 12.
__global__ __launch_bounds__(256) void ffn1_kernel(
    const u16* __restrict__ xb, const float* __restrict__ w1,
    const int* __restrict__ tos, const int* __restrict__ seg,
    u16* __restrict__ hbuf)
{
  const int fid = blockIdx.x;
  const int mt = fid / 48, nt = fid % 48;
  int m0;
  const int e = find_expert(seg, mt, &m0);
  if (e < 0) return;
  const int cnt   = seg[NE + e];
  const int start = seg[e];
  const int n0    = nt * 64;

  __shared__ __align__(16) u16 As[2][64 * 64];
  __shared__ __align__(16) u16 Bs[2][64 * 64];
  __shared__ int toks[64];

  const int tid = threadIdx.x;
  if (tid < 64) toks[tid] = tos[start + min(m0 + tid, cnt - 1)];
  __syncthreads();

  const int lane = tid & 63;
  const int wid  = tid >> 6;
  const int rsub = lane >> 3;
  const int c8   = (lane & 7) ^ rsub;

  // A gather addressing (2 DMA issues/wave, 8 rows each)
  const u16* ag[2]; int ao[2];
#pragma unroll
  for (int i = 0; i < 2; ++i) {
    const int rb = wid * 8 + i * 32;
    ag[i] = xb + (size_t)toks[rb + rsub] * HD + c8 * 8;
    ao[i] = rb * 64;
  }

  // B staging addressing
  const int rr2 = tid >> 5;          // k-octet 0..7
  const int np  = tid & 31;          // n-pair
  const float* bsrc = w1 + (size_t)e * HD * FF + n0 + np * 2;
  const int wof0 = (np * 2) * 64 + ((rr2 ^ (np & 7)) << 3);
  const int wof1 = wof0 + 64;

  const int wm  = (wid >> 1) << 5;   // 0 / 32 (m)
  const int wn  = (wid & 1) << 5;    // 0 / 32 (n)
  const int q   = lane >> 4;
  const int r16 = lane & 15;

  f32x4 acc[2][2] = {};
  float2 breg0[8], breg1[8];

  // prologue
  LOADB(bsrc, FF, 0, breg0);
  LOADB(bsrc, FF, BK, breg1);
#pragma unroll
  for (int i = 0; i < 2; ++i) load16(ag[i], &As[0][ao[i]]);
  WRITEB(breg0, &Bs[0][0]);
  __syncthreads();

#pragma unroll
  for (int kk = 0; kk < 12; ++kk) {
    const int cur = kk & 1, nxt = cur ^ 1;
    if (kk + 2 < 12) {                       // prefetch regs for k+2 FIRST
      if (cur == 0) LOADB(bsrc, FF, (kk + 2) * BK, breg0);
      else          LOADB(bsrc, FF, (kk + 2) * BK, breg1);
    }
    if (kk + 1 < 12) {
#pragma unroll
      for (int i = 0; i < 2; ++i) load16(ag[i] + (kk + 1) * BK, &As[nxt][ao[i]]);
      if (nxt == 0) WRITEB(breg0, &Bs[0][0]);
      else          WRITEB(breg1, &Bs[1][0]);
    }
    MFMA_STEP(As[cur], Bs[cur]);
    __syncthreads();
  }

  // epilogue: gelu + bf16 store
#pragma unroll
  for (int t = 0; t < 2; ++t) {
    const int mbase = m0 + wm + t * 16 + q * 4;
#pragma unroll
    for (int i = 0; i < 4; ++i) {
      if (mbase + i < cnt) {
        u16* drow = hbuf + (size_t)(start + mbase + i) * FF + n0 + wn;
#pragma unroll
        for (int c = 0; c < 2; ++c) {
          float vv = acc[t][c][i];
          vv = 0.5f * vv * (1.0f + erff(vv * 0.70710678118f));
          drow[c * 16 + r16] = f2bf(vv);
        }
      }
    }
  }
}

// FFN2: out += gate * (h @ w2[e]), K-split x4, atomic fp32 accumulate. NSTEP=12.
__global__ __launch_bounds__(256) void ffn2_kernel(
    const u16* __restrict__ hbuf, const float* __restrict__ w2,
    const int* __restrict__ tos, const float* __restrict__ gos,
    const int* __restrict__ seg, float* __restrict__ out)
{
  const int u    = blockIdx.x;
  const int mt   = u / 48;
  const int rest = u % 48;
  const int n0   = (rest >> 2) * 64;   // 12 n-tiles
  const int ks   = rest & 3;
  int m0;
  const int e = find_expert(seg, mt, &m0);
  if (e < 0) return;
  const int cnt   = seg[NE + e];
  const int start = seg[e];
  const int kbase = ks * KSEG;

  __shared__ __align__(16) u16 As[2][64 * 64];
  __shared__ __align__(16) u16 Bs[2][64 * 64];
  __shared__ int   toks[64];
  __shared__ float gates[64];

  const int tid = threadIdx.x;
  if (tid < 64) {
    const int idx = start + min(m0 + tid, cnt - 1);
    toks[tid]  = tos[idx];
    gates[tid] = gos[idx];
  }
  __syncthreads();

  const int lane = tid & 63;
  const int wid  = tid >> 6;
  const int rsub = lane >> 3;
  const int c8   = (lane & 7) ^ rsub;

  const u16* ag[2]; int ao[2];
#pragma unroll
  for (int i = 0; i < 2; ++i) {
    const int rb = wid * 8 + i * 32;
    ag[i] = hbuf + (size_t)(start + min(m0 + rb + rsub, cnt - 1)) * FF + kbase + c8 * 8;
    ao[i] = rb * 64;
  }

  const int rr2 = tid >> 5;
  const int np  = tid & 31;
  const float* bsrc = w2 + (size_t)e * FF * HD + (size_t)kbase * HD + n0 + np * 2;
  const int wof0 = (np * 2) * 64 + ((rr2 ^ (np & 7)) << 3);
  const int wof1 = wof0 + 64;

  const int wm  = (wid >> 1) << 5;
  const int wn  = (wid & 1) << 5;
  const int q   = lane >> 4;
  const int r16 = lane & 15;

  f32x4 acc[2][2] = {};
  float2 breg0[8], breg1[8];

  LOADB(bsrc, HD, 0, breg0);
  LOADB(bsrc, HD, BK, breg1);
#pragma unroll
  for (int i = 0; i < 2; ++i) load16(ag[i], &As[0][ao[i]]);
  WRITEB(breg0, &Bs[0][0]);
  __syncthreads();

#pragma unroll
  for (int kk = 0; kk < 12; ++kk) {
    const int cur = kk & 1, nxt = cur ^ 1;
    if (kk + 2 < 12) {
      if (cur == 0) LOADB(bsrc, HD, (kk + 2) * BK, breg0);
      else          LOADB(bsrc, HD, (kk + 2) * BK, breg1);
    }
    if (kk + 1 < 12) {
#pragma unroll
      for (int i = 0; i < 2; ++i) load16(ag[i] + (kk + 1) * BK, &As[nxt][ao[i]]);
      if (nxt == 0) WRITEB(breg0, &Bs[0][0]);
      else          WRITEB(breg1, &Bs[1][0]);
    }
    MFMA_STEP(As[cur], Bs[cur]);
    __syncthreads();
  }

#pragma unroll
  for (int t = 0; t < 2; ++t) {
    const int mbase = wm + t * 16 + q * 4;
#pragma unroll
    for (int i = 0; i < 4; ++i) {
      const int mloc = mbase + i;
      if (m0 + mloc < cnt) {
        const int tok  = toks[mloc];
        const float gv = gates[mloc];
        float* drow = out + (size_t)tok * HD + n0 + wn;
#pragma unroll
        for (int c = 0; c < 2; ++c)
          atomicAdd(drow + c * 16 + r16, gv * acc[t][c][i]);
      }
    }
  }
}

// ---------------------------------------------------------------------------
extern "C" void kernel_launch(void* const* d_in, const int* in_sizes, int n_in,
                              void* d_out, int out_size, void* d_ws, size_t ws_size,
                              hipStream_t stream) {
  const float* x  = (const float*)d_in[0];
  const float* rw = (const float*)d_in[1];
  const float* w1 = (const float*)d_in[2];
  const float* w2 = (const float*)d_in[3];
  float* out = (float*)d_out;

  char* ws = (char*)d_ws;
  const size_t o_xb    = 0;
  const size_t o_hbuf  = o_xb + (size_t)NTOK * HD * 2;
  const size_t o_tos   = o_hbuf + (size_t)NSLOT * FF * 2;
  const size_t o_gos   = o_tos + (size_t)NSLOT * 4;
  const size_t o_seg   = o_gos + (size_t)NSLOT * 4;
  const size_t o_ctr   = o_seg + 64 * 4;
  const size_t o_ti    = o_ctr + 64;
  const size_t o_tg    = o_ti + (size_t)NSLOT * 4;
  u16*   xb    = (u16*)(ws + o_xb);
  u16*   hbuf  = (u16*)(ws + o_hbuf);
  int*   tos   = (int*)(ws + o_tos);
  float* gos   = (float*)(ws + o_gos);
  int*   seg   = (int*)(ws + o_seg);
  int*   ctr   = (int*)(ws + o_ctr);
  int*   ti    = (int*)(ws + o_ti);
  float* tg    = (float*)(ws + o_tg);

  hipMemsetAsync(ctr, 0, 64, stream);
  hipLaunchKernelGGL(router_kernel, dim3(NB_ROUTER), dim3(256), 0, stream,
                     x, rw, xb, ti, tg, tos, gos, seg, ctr, out);
  hipLaunchKernelGGL(ffn1_kernel, dim3(NU_FFN1), dim3(256), 0, stream,
                     xb, w1, tos, seg, hbuf);
  hipLaunchKernelGGL(ffn2_kernel, dim3(NU_FFN2), dim3(256), 0, stream,
                     hbuf, w2, tos, gos, seg, out);
}